// Round 2
// baseline (5356.771 us; speedup 1.0000x reference)
//
#include <hip/hip_runtime.h>
#include <math.h>
#include <float.h>

// ResidualVectorQuantizer — Round 2: exact np-f32 formula replication.
//
// np ref model:  G = r @ W.T        (BLAS sgemm: per-element sequential-k FMA chain)
//                dist = fl(fl(sq_r + sq_w) - fl(2*G))   (elementwise f32)
//                idx  = argmin, first occurrence (lex-min on (dist, k))
//                sq_r/sq_w = numpy pairwise sum of fl(v*v), n=256 (128+128 blocks,
//                            8 interleaved accumulators, fixed combine tree)
// Fast path: order-free f32 GEMM ranks candidates; |np_dist - approx| bounded by
// ~3.2e-5 (two roundings at magnitude 256 + dot-order diffs). If global approx
// top-2 gap > MARGIN=1.2e-4 -> approx winner IS the np argmin. Else rescore the
// within-margin members of the global top-4 with the exact np formula.

#define N_ROWS 65536
#define DIM    256
#define K_NUM  1024
#define N_CB   4
#define RPB    32
#define TK     32
#define QOFF   16777216     // N_ROWS*DIM
#define IDXOFF 16777219     // QOFF + 3 scalars
#define NPAIRS 523776
#define MARGIN 1.2e-4f

#define SWZV(row, dunit) ((row) * DIM + ((((dunit) ^ ((row) & 7))) << 1))
#define SWZ2(row, d)     ((row) * DIM + ((((((d) >> 1) ^ ((row) & 7))) << 1) | ((d) & 1)))

// ---------------- ws layout ----------------
// [0, 32768)      double wn64[4096]      (pdist only)
// [32768, 49152)  float  sqw[4096]       (np-exact ||w||^2)
// [49152, 65536)  int    counts[4096]
// [65536, 65568)  double sse[4]
// [65568, 65576)  double pdacc[1]

__device__ __forceinline__ bool lexless(float a, int ka, float b, int kb) {
  return (a < b) || (a == b && ka < kb);
}

__global__ void zero_ws(int* counts, double* sse, double* pdacc) {
  int t = blockIdx.x * blockDim.x + threadIdx.x;
  if (t < 4096) counts[t] = 0;
  if (t < 4) sse[t] = 0.0;
  if (t == 0) pdacc[0] = 0.0;
}

__global__ void wnorm_kernel(const float* __restrict__ cb,
                             double* __restrict__ wn64) {
  int gw = blockIdx.x * 4 + (threadIdx.x >> 6);
  int lane = threadIdx.x & 63;
  const float* row = cb + (size_t)gw * DIM;
  float4 v = *(const float4*)(row + lane * 4);
  double s = (double)v.x * v.x + (double)v.y * v.y +
             (double)v.z * v.z + (double)v.w * v.w;
#pragma unroll
  for (int off = 32; off; off >>= 1) s += __shfl_xor(s, off, 64);
  if (lane == 0) wn64[gw] = s;
}

// np-exact sum(W*W, axis=1): pairwise structure for n=256
__global__ void np_sqw_kernel(const float* __restrict__ cb,
                              float* __restrict__ sqw) {
#pragma clang fp contract(off)
  int g = blockIdx.x * blockDim.x + threadIdx.x;  // 0..4095
  const float* row = cb + (size_t)g * DIM;
  float blk[2];
#pragma unroll
  for (int b = 0; b < 2; ++b) {
    const float* a = row + b * 128;
    float r[8];
#pragma unroll
    for (int j = 0; j < 8; ++j) { float v = a[j]; r[j] = v * v; }
    for (int i = 8; i < 128; i += 8) {
#pragma unroll
      for (int j = 0; j < 8; ++j) { float v = a[i + j]; r[j] = r[j] + v * v; }
    }
    blk[b] = ((r[0] + r[1]) + (r[2] + r[3])) + ((r[4] + r[5]) + (r[6] + r[7]));
  }
  sqw[g] = blk[0] + blk[1];
}

__global__ void pdist_kernel(const float* __restrict__ cb,
                             const double* __restrict__ wn64,
                             double* __restrict__ pdacc) {
  __shared__ float wi[DIM];
  int c = blockIdx.x >> 10;
  int i = blockIdx.x & 1023;
  int t = threadIdx.x;  // 128 threads
  const float* rowi = cb + ((size_t)c * K_NUM + i) * DIM;
  *(float2*)&wi[t * 2] = *(const float2*)&rowi[t * 2];
  __syncthreads();
  double bi = wn64[c * K_NUM + i];
  double lsum = 0.0;
  for (int j = i + 1 + t; j < K_NUM; j += 128) {
    const float* rowj = cb + ((size_t)c * K_NUM + j) * DIM;
    double dot = 0.0;
#pragma unroll 8
    for (int d = 0; d < DIM; ++d) dot += (double)rowj[d] * (double)wi[d];
    double d2 = bi + wn64[c * K_NUM + j] - 2.0 * dot;
    lsum += sqrt(fmax(d2, 0.0));
  }
#pragma unroll
  for (int off = 32; off; off >>= 1) lsum += __shfl_xor(lsum, off, 64);
  if ((t & 63) == 0) atomicAdd(pdacc, lsum);
}

__global__ __launch_bounds__(128) void rvq_main(
    const float* __restrict__ x, const float* __restrict__ cb,
    const float* __restrict__ sqw,
    int* __restrict__ counts, double* __restrict__ sse,
    float* __restrict__ out) {
  __shared__ float Wt[RPB * DIM];    // codebook tile (reused as idx buffer)
  __shared__ float resS[RPB * DIM];  // residual tile

  int t = threadIdx.x;       // 0..127
  int kg = t & 7;            // lane within row-group
  int rg = t >> 3;           // row group 0..15; rows rg and rg+16
  int rb = blockIdx.x * RPB;

  // stage residual = x
#pragma unroll 4
  for (int it = 0; it < RPB; ++it) {
    float2 v = *(const float2*)&x[(size_t)(rb + it) * DIM + t * 2];
    *(float2*)&resS[SWZV(it, t)] = v;
  }
  __syncthreads();

  for (int c = 0; c < N_CB; ++c) {
    const float* cbl = cb + (size_t)c * K_NUM * DIM;
    const float* sqwl = sqw + c * K_NUM;

    // ---- np-exact sq_r for rows rg, rg+16 (8-lane pairwise replica) ----
    float sqr[2];
    {
#pragma clang fp contract(off)
#pragma unroll
      for (int j = 0; j < 2; ++j) {
        int row = rg + 16 * j;
        float blk[2];
#pragma unroll
        for (int b = 0; b < 2; ++b) {
          float v0 = resS[SWZ2(row, b * 128 + kg)];
          float acc = v0 * v0;
          for (int i = 1; i < 16; ++i) {
            float v = resS[SWZ2(row, b * 128 + kg + 8 * i)];
            acc = acc + v * v;
          }
          acc = acc + __shfl_xor(acc, 1, 8);
          acc = acc + __shfl_xor(acc, 2, 8);
          acc = acc + __shfl_xor(acc, 4, 8);
          blk[b] = acc;
        }
        sqr[j] = blk[0] + blk[1];
      }
    }

    // ---- stage 1: approx scores, per-lane top-2 (k ≡ kg mod 8 partition) ----
    float m1[2], m2[2]; int i1[2], i2[2];
    m1[0] = m1[1] = m2[0] = m2[1] = FLT_MAX;
    i1[0] = i1[1] = i2[0] = i2[1] = 0x7FFFFFFF;

    for (int tile = 0; tile < K_NUM / TK; ++tile) {
      __syncthreads();
      const float* wsrc = cbl + (size_t)tile * TK * DIM;
#pragma unroll 4
      for (int it = 0; it < TK; ++it) {
        float2 v = *(const float2*)&wsrc[(size_t)it * DIM + t * 2];
        *(float2*)&Wt[SWZV(it, t)] = v;
      }
      __syncthreads();

      float acc[4][2] = {{0.f, 0.f}, {0.f, 0.f}, {0.f, 0.f}, {0.f, 0.f}};
#pragma unroll 8
      for (int du = 0; du < DIM / 2; ++du) {
        float2 r0 = *(const float2*)&resS[SWZV(rg, du)];
        float2 r1 = *(const float2*)&resS[SWZV(rg + 16, du)];
#pragma unroll
        for (int i = 0; i < 4; ++i) {
          int k = kg + 8 * i;
          float2 w = *(const float2*)&Wt[SWZV(k, du)];
          acc[i][0] += w.x * r0.x; acc[i][0] += w.y * r0.y;
          acc[i][1] += w.x * r1.x; acc[i][1] += w.y * r1.y;
        }
      }

#pragma unroll
      for (int i = 0; i < 4; ++i) {
        int k = tile * TK + kg + 8 * i;
        float b = sqwl[k];
#pragma unroll
        for (int j = 0; j < 2; ++j) {
          float s = b - 2.0f * acc[i][j];
          if (lexless(s, k, m1[j], i1[j])) {
            m2[j] = m1[j]; i2[j] = i1[j]; m1[j] = s; i1[j] = k;
          } else if (lexless(s, k, m2[j], i2[j])) {
            m2[j] = s; i2[j] = k;
          }
        }
      }
    }  // tiles

    // ---- global top-4 via bitonic butterfly over the 8 kg lanes ----
    float as[2][4]; int ak[2][4];
#pragma unroll
    for (int j = 0; j < 2; ++j) {
      as[j][0] = m1[j]; ak[j][0] = i1[j];
      as[j][1] = m2[j]; ak[j][1] = i2[j];
      as[j][2] = FLT_MAX; ak[j][2] = 0x7FFFFFFF;
      as[j][3] = FLT_MAX; ak[j][3] = 0x7FFFFFFF;
#pragma unroll
      for (int off = 1; off <= 4; off <<= 1) {
        float bs[4]; int bk[4];
#pragma unroll
        for (int q = 0; q < 4; ++q) {
          bs[q] = __shfl_xor(as[j][q], off, 8);
          bk[q] = __shfl_xor(ak[j][q], off, 8);
        }
        // lower half of bitonic merge: c[q] = lexmin(a[q], b[3-q])
        float cs[4]; int ck[4];
#pragma unroll
        for (int q = 0; q < 4; ++q) {
          bool ta = lexless(as[j][q], ak[j][q], bs[3 - q], bk[3 - q]);
          cs[q] = ta ? as[j][q] : bs[3 - q];
          ck[q] = ta ? ak[j][q] : bk[3 - q];
        }
        // bitonic sort-4: CE(0,2) CE(1,3) CE(0,1) CE(2,3)
#define CE(p, q) { bool sw = lexless(cs[q], ck[q], cs[p], ck[p]); \
                   float ts = sw ? cs[q] : cs[p]; int tk = sw ? ck[q] : ck[p]; \
                   cs[q] = sw ? cs[p] : cs[q]; ck[q] = sw ? ck[p] : ck[q]; \
                   cs[p] = ts; ck[p] = tk; }
        CE(0, 2) CE(1, 3) CE(0, 1) CE(2, 3)
#undef CE
#pragma unroll
        for (int q = 0; q < 4; ++q) { as[j][q] = cs[q]; ak[j][q] = ck[q]; }
      }
    }

    // ---- winner: easy path, or np-exact rescore of within-margin top-4 ----
    int winner[2];
#pragma unroll
    for (int j = 0; j < 2; ++j) {
      if (as[j][1] <= as[j][0] + MARGIN) {
        int row = rg + 16 * j;
        // select this lane's slot without dynamic register indexing
        float ss = (kg == 0) ? as[j][0] : (kg == 1) ? as[j][1]
                 : (kg == 2) ? as[j][2] : (kg == 3) ? as[j][3] : FLT_MAX;
        int   sk = (kg == 0) ? ak[j][0] : (kg == 1) ? ak[j][1]
                 : (kg == 2) ? ak[j][2] : (kg == 3) ? ak[j][3] : 0x7FFFFFFF;
        float myd = FLT_MAX; int myk = 0x7FFFFFFF;
        if (kg < 4 && ss <= as[j][0] + MARGIN) {
          const float* wrow = cbl + (size_t)sk * DIM;
          float g = 0.0f;
#pragma unroll 8
          for (int d = 0; d < DIM; ++d)
            g = __builtin_fmaf(wrow[d], resS[SWZ2(row, d)], g);
          float T = sqr[j] + sqwl[sk];   // fl(sq_r + sq_w)
          myd = T - 2.0f * g;            // fl(T - 2g)  (2g exact)
          myk = sk;
        }
#pragma unroll
        for (int off = 1; off <= 4; off <<= 1) {
          float od = __shfl_xor(myd, off, 8);
          int   ok = __shfl_xor(myk, off, 8);
          if (lexless(od, ok, myd, myk)) { myd = od; myk = ok; }
        }
        winner[j] = myk;
      } else {
        winner[j] = ak[j][0];
      }
    }

    __syncthreads();              // Wt dead -> reuse as idx buffer
    int* idxS = (int*)Wt;
    if (kg == 0) {
      idxS[rg] = winner[0];
      idxS[rg + 16] = winner[1];
      out[(size_t)IDXOFF + (size_t)c * N_ROWS + rb + rg] = (float)winner[0];
      out[(size_t)IDXOFF + (size_t)c * N_ROWS + rb + rg + 16] = (float)winner[1];
      atomicAdd(&counts[c * K_NUM + winner[0]], 1);
      atomicAdd(&counts[c * K_NUM + winner[1]], 1);
    }
    __syncthreads();

    // ---- update: exact f32 chain (q_st, quantized, residual) ----
    double lsse = 0.0;
#pragma unroll 4
    for (int it = 0; it < RPB; ++it) {
      int widx = idxS[it];
      size_t go = (size_t)(rb + it) * DIM + t * 2;
      float2 wv = *(const float2*)&cbl[(size_t)widx * DIM + t * 2];
      float2 rv = *(const float2*)&resS[SWZV(it, t)];
      float ex = wv.x - rv.x, ey = wv.y - rv.y;     // e = q - r
      float qsx = rv.x + ex, qsy = rv.y + ey;       // q_st = r + e
      float qnx, qny;
      if (c == 0) { qnx = qsx; qny = qsy; }
      else { float2 qo = *(const float2*)&out[go]; qnx = qo.x + qsx; qny = qo.y + qsy; }
      *(float2*)&out[go] = make_float2(qnx, qny);
      float2 xv = *(const float2*)&x[go];
      float rnx = xv.x - qnx, rny = xv.y - qny;     // res = x - quantized
      *(float2*)&resS[SWZV(it, t)] = make_float2(rnx, rny);
      lsse += (double)ex * (double)ex + (double)ey * (double)ey;
    }
#pragma unroll
    for (int off = 32; off; off >>= 1) lsse += __shfl_xor(lsse, off, 64);
    if ((t & 63) == 0) atomicAdd(&sse[c], lsse);
    __syncthreads();
  }  // levels
}

__global__ void finalize_kernel(const int* __restrict__ counts,
                                const double* __restrict__ sse,
                                const double* __restrict__ pdacc,
                                float* __restrict__ out) {
  __shared__ double red[1024];
  int t = threadIdx.x;
  double u = 0.0;
#pragma unroll
  for (int c = 0; c < 4; ++c) u += fabs((double)counts[c * 1024 + t] - 64.0);
  red[t] = u;
  __syncthreads();
  for (int s = 512; s; s >>= 1) {
    if (t < s) red[t] += red[t + s];
    __syncthreads();
  }
  if (t == 0) {
    double q = 0.0;
#pragma unroll
    for (int c = 0; c < 4; ++c) q += sse[c];
    q *= 1.25 / ((double)N_ROWS * (double)DIM);
    out[QOFF + 0] = (float)q;
    out[QOFF + 1] = (float)(red[0] / 1024.0);
    out[QOFF + 2] = (float)(2.0 * pdacc[0] / (double)NPAIRS);
  }
}

extern "C" void kernel_launch(void* const* d_in, const int* in_sizes, int n_in,
                              void* d_out, int out_size, void* d_ws, size_t ws_size,
                              hipStream_t stream) {
  const float* x  = (const float*)d_in[0];
  const float* cb = (const float*)d_in[1];
  float* out = (float*)d_out;

  char* w = (char*)d_ws;
  double* wn64  = (double*)(w);
  float*  sqw   = (float*) (w + 32768);
  int*    counts= (int*)   (w + 49152);
  double* sse   = (double*)(w + 65536);
  double* pdacc = (double*)(w + 65568);

  zero_ws<<<16, 256, 0, stream>>>(counts, sse, pdacc);
  wnorm_kernel<<<1024, 256, 0, stream>>>(cb, wn64);
  np_sqw_kernel<<<16, 256, 0, stream>>>(cb, sqw);
  pdist_kernel<<<4096, 128, 0, stream>>>(cb, wn64, pdacc);
  rvq_main<<<N_ROWS / RPB, 128, 0, stream>>>(x, cb, sqw, counts, sse, out);
  finalize_kernel<<<1, 1024, 0, stream>>>(counts, sse, pdacc, out);
}

// Round 3
// 1783.306 us; speedup vs baseline: 3.0038x; 3.0038x over previous
//
#include <hip/hip_runtime.h>
#include <math.h>
#include <float.h>

// ResidualVectorQuantizer — Round 3: fp16-MFMA scoring + exact np-f32 argmin rescue.
//
// np ref model (verified exact in R2, absmax 0):
//   G = r @ W.T            (BLAS sgemm: per-element sequential-k FMA chain)
//   dist = fl(fl(sq_r + sq_w) - fl(2*G))   elementwise f32
//   idx  = argmin, first occurrence (lex-min on (dist, k))
//   sq_r/sq_w = numpy pairwise sum (n=256: two 128-blocks, 8 accumulators)
// Stage 1 here ranks with fp16 MFMA (error <=~3e-5 @6sigma) + np rounding model
// (<=3.2e-5) -> MARGIN 2.4e-4. Within-margin shortlist rescored with the exact
// np formula (sequential fmaf chain), lex-(dist,k) winner.

#define N_ROWS 65536
#define DIM    256
#define K_NUM  1024
#define N_CB   4
#define RPB    32
#define QOFF   16777216     // N_ROWS*DIM
#define IDXOFF 16777219     // QOFF + 3 scalars
#define NPAIRS 523776
#define MARGIN 2.4e-4f

#define SWZV(row, dunit) ((row) * DIM + ((((dunit) ^ ((row) & 7))) << 1))
#define SWZ2(row, d)     ((row) * DIM + ((((((d) >> 1) ^ ((row) & 7))) << 1) | ((d) & 1)))

typedef _Float16 f16x8 __attribute__((ext_vector_type(8)));
typedef float    f32x4 __attribute__((ext_vector_type(4)));

// ---------------- ws layout (both paths) ----------------
// [0, 32768)        double wn64[4096]         (pdist)
// [32768, 49152)    float  sqw[4096]          (np-exact ||w||^2)
// [49152, 65536)    int    counts[4096]
// [65536, 65568)    double sse[4]
// [65568, 65576)    double pdacc[1]
// [69632, 2166784)  _Float16 bws[1048576]     (fp16 codebooks, fragment-major; MFMA path)
#define WS_BWS_OFF 69632
#define WS_NEEDED  2166784

__device__ __forceinline__ bool lexless(float a, int ka, float b, int kb) {
  return (a < b) || (a == b && ka < kb);
}

__global__ void zero_ws(int* counts, double* sse, double* pdacc) {
  int t = blockIdx.x * blockDim.x + threadIdx.x;
  if (t < 4096) counts[t] = 0;
  if (t < 4) sse[t] = 0.0;
  if (t == 0) pdacc[0] = 0.0;
}

__global__ void wnorm_kernel(const float* __restrict__ cb,
                             double* __restrict__ wn64) {
  int gw = blockIdx.x * 4 + (threadIdx.x >> 6);
  int lane = threadIdx.x & 63;
  const float* row = cb + (size_t)gw * DIM;
  float4 v = *(const float4*)(row + lane * 4);
  double s = (double)v.x * v.x + (double)v.y * v.y +
             (double)v.z * v.z + (double)v.w * v.w;
#pragma unroll
  for (int off = 32; off; off >>= 1) s += __shfl_xor(s, off, 64);
  if (lane == 0) wn64[gw] = s;
}

// np-exact sum(W*W, axis=1): pairwise structure for n=256
__global__ void np_sqw_kernel(const float* __restrict__ cb,
                              float* __restrict__ sqw) {
#pragma clang fp contract(off)
  int g = blockIdx.x * blockDim.x + threadIdx.x;  // 0..4095
  const float* row = cb + (size_t)g * DIM;
  float blk[2];
#pragma unroll
  for (int b = 0; b < 2; ++b) {
    const float* a = row + b * 128;
    float r[8];
#pragma unroll
    for (int j = 0; j < 8; ++j) { float v = a[j]; r[j] = v * v; }
    for (int i = 8; i < 128; i += 8) {
#pragma unroll
      for (int j = 0; j < 8; ++j) { float v = a[i + j]; r[j] = r[j] + v * v; }
    }
    blk[b] = ((r[0] + r[1]) + (r[2] + r[3])) + ((r[4] + r[5]) + (r[6] + r[7]));
  }
  sqw[g] = blk[0] + blk[1];
}

// codebooks -> fp16, fragment-major for mfma_f32_16x16x32_f16 B operand.
// frag F = (c*64 + nt)*8 + kk holds B[d=kk*32+quad*8+j][n=nt*16+nin] at
// element offset F*512 + (quad*16+nin)*8 + j.
__global__ void cvt_b_kernel(const float* __restrict__ cb,
                             _Float16* __restrict__ bws) {
  int tg = blockIdx.x * blockDim.x + threadIdx.x;  // 131072 threads
  int row = tg >> 5;        // global codebook row 0..4095
  int chunk = tg & 31;      // 8-wide d chunk
  int c = row >> 10, n = row & 1023;
  int nt = n >> 4, nin = n & 15;
  int kk = chunk >> 2, quad = chunk & 3;
  const float* src = cb + (size_t)row * DIM + chunk * 8;
  f16x8 h;
#pragma unroll
  for (int j = 0; j < 8; ++j) h[j] = (_Float16)src[j];
  size_t dst = ((size_t)((c * 64 + nt) * 8 + kk) * 64 + quad * 16 + nin) * 8;
  *(f16x8*)(bws + dst) = h;
}

__global__ void pdist_kernel(const float* __restrict__ cb,
                             const double* __restrict__ wn64,
                             double* __restrict__ pdacc) {
  __shared__ float wi[DIM];
  int c = blockIdx.x >> 10;
  int i = blockIdx.x & 1023;
  int t = threadIdx.x;  // 128 threads
  const float* rowi = cb + ((size_t)c * K_NUM + i) * DIM;
  *(float2*)&wi[t * 2] = *(const float2*)&rowi[t * 2];
  __syncthreads();
  double bi = wn64[c * K_NUM + i];
  double lsum = 0.0;
  for (int j = i + 1 + t; j < K_NUM; j += 128) {
    const float* rowj = cb + ((size_t)c * K_NUM + j) * DIM;
    double dot = 0.0;
#pragma unroll 8
    for (int d = 0; d < DIM; ++d) dot += (double)rowj[d] * (double)wi[d];
    double d2 = bi + wn64[c * K_NUM + j] - 2.0 * dot;
    lsum += sqrt(fmax(d2, 0.0));
  }
#pragma unroll
  for (int off = 32; off; off >>= 1) lsum += __shfl_xor(lsum, off, 64);
  if ((t & 63) == 0) atomicAdd(pdacc, lsum);
}

// ================= MFMA main kernel =================
__global__ __launch_bounds__(256) void rvq_main_mfma(
    const float* __restrict__ x, const float* __restrict__ cb,
    const _Float16* __restrict__ bws, const float* __restrict__ sqw,
    int* __restrict__ counts, double* __restrict__ sse,
    float* __restrict__ out) {
  __shared__ float resS[RPB * DIM];            // 32 KB, swizzled f32 residual
  __shared__ __align__(16) char afbuf[16384];  // Af frags / (overlaid) candidate bufs
  __shared__ float sqrS[RPB];

  _Float16* Af   = (_Float16*)afbuf;           // 16 frags * 64 lanes * 8 f16
  float* candS   = (float*)afbuf;              // [32][16]
  int*   candI   = (int*)(afbuf + 2048);       // [32][16]
  int*   hardCnt = (int*)(afbuf + 4096);       // [32]
  int*   hardIdx = (int*)(afbuf + 4224);       // [32][6]
  int*   idxS    = (int*)(afbuf + 4992);       // [32]

  int t = threadIdx.x;            // 0..255
  int lane = t & 63, wq = t >> 6; // wave lane / wave id
  int quad = lane >> 4;
  int rb = blockIdx.x * RPB;
  int d2 = t & 127, rh = t >> 7;  // update/staging mapping

  // stage residual = x
#pragma unroll 4
  for (int i = 0; i < 16; ++i) {
    int row = rh * 16 + i;
    float2 v = *(const float2*)&x[(size_t)(rb + row) * DIM + d2 * 2];
    *(float2*)&resS[SWZV(row, d2)] = v;
  }
  __syncthreads();

  for (int c = 0; c < N_CB; ++c) {
    const float* cbl = cb + (size_t)c * K_NUM * DIM;
    const float* sqwl = sqw + c * K_NUM;

    // ---- ph0: np-exact sq_r per row (8-lane pairwise replica) ----
    {
#pragma clang fp contract(off)
      int kg = t & 7, rg = t >> 3;
      float blk[2];
#pragma unroll
      for (int b = 0; b < 2; ++b) {
        float v0 = resS[SWZ2(rg, b * 128 + kg)];
        float acc = v0 * v0;
        for (int i = 1; i < 16; ++i) {
          float v = resS[SWZ2(rg, b * 128 + kg + 8 * i)];
          acc = acc + v * v;
        }
        acc = acc + __shfl_xor(acc, 1, 8);
        acc = acc + __shfl_xor(acc, 2, 8);
        acc = acc + __shfl_xor(acc, 4, 8);
        blk[b] = acc;
      }
      if (kg == 0) sqrS[rg] = blk[0] + blk[1];
    }

    // ---- ph1: residual -> fp16 A fragments in LDS ----
#pragma unroll
    for (int rep = 0; rep < 4; ++rep) {
      int slot = t + rep * 256;            // 0..1023
      int frag = slot >> 6, l6 = slot & 63;
      int mt = frag >> 3, kk = frag & 7;
      int m = mt * 16 + (l6 & 15), d0 = kk * 32 + (l6 >> 4) * 8;
      f16x8 h;
#pragma unroll
      for (int j = 0; j < 8; ++j) h[j] = (_Float16)resS[SWZ2(m, d0 + j)];
      *(f16x8*)(Af + slot * 8) = h;
    }
    __syncthreads();

    // ---- ph2: MFMA scoring, per-lane top-2 per (mt,reg) slot ----
    float s1[2][4], s2[2][4]; int k1[2][4], k2[2][4];
#pragma unroll
    for (int mt = 0; mt < 2; ++mt)
#pragma unroll
      for (int r = 0; r < 4; ++r) {
        s1[mt][r] = FLT_MAX; s2[mt][r] = FLT_MAX;
        k1[mt][r] = 0x7FFFFFFF; k2[mt][r] = 0x7FFFFFFF;
      }

#pragma unroll 1
    for (int g = 0; g < 4; ++g) {
      f32x4 acc[2][4];
#pragma unroll
      for (int mt = 0; mt < 2; ++mt)
#pragma unroll
        for (int u = 0; u < 4; ++u) acc[mt][u] = (f32x4){0.f, 0.f, 0.f, 0.f};

      const _Float16* B0 = bws +
          (size_t)((c * 64 + wq * 16 + g * 4) * 8) * 512 + lane * 8;
#pragma unroll
      for (int kk = 0; kk < 8; ++kk) {
        f16x8 a0 = *(const f16x8*)(Af + ((0 * 8 + kk) * 64 + lane) * 8);
        f16x8 a1 = *(const f16x8*)(Af + ((1 * 8 + kk) * 64 + lane) * 8);
#pragma unroll
        for (int u = 0; u < 4; ++u) {
          f16x8 bu = *(const f16x8*)(B0 + (size_t)(u * 8 + kk) * 512);
          acc[0][u] = __builtin_amdgcn_mfma_f32_16x16x32_f16(a0, bu, acc[0][u], 0, 0, 0);
          acc[1][u] = __builtin_amdgcn_mfma_f32_16x16x32_f16(a1, bu, acc[1][u], 0, 0, 0);
        }
      }
      // epilogue: scores + top-2 (plain float order; ties resolved by hard path)
#pragma unroll
      for (int u = 0; u < 4; ++u) {
        int n = (wq * 16 + g * 4 + u) * 16 + (lane & 15);
        float w2 = sqwl[n];
#pragma unroll
        for (int mt = 0; mt < 2; ++mt)
#pragma unroll
          for (int r = 0; r < 4; ++r) {
            float s = w2 - 2.0f * acc[mt][u][r];
            if (s < s1[mt][r]) {
              s2[mt][r] = s1[mt][r]; k2[mt][r] = k1[mt][r];
              s1[mt][r] = s;         k1[mt][r] = n;
            } else if (s < s2[mt][r]) {
              s2[mt][r] = s; k2[mt][r] = n;
            }
          }
      }
    }
    __syncthreads();   // all waves done reading Af -> cand bufs may overwrite

    // ---- ph3: per-wave top-4 per row (bitonic over 16 lanes of quad) ----
    {
      float sA[2][4][4]; int kA[2][4][4];
#pragma unroll
      for (int mt = 0; mt < 2; ++mt)
#pragma unroll
        for (int r = 0; r < 4; ++r) {
          sA[mt][r][0] = s1[mt][r]; kA[mt][r][0] = k1[mt][r];
          sA[mt][r][1] = s2[mt][r]; kA[mt][r][1] = k2[mt][r];
          sA[mt][r][2] = FLT_MAX;   kA[mt][r][2] = 0x7FFFFFFF;
          sA[mt][r][3] = FLT_MAX;   kA[mt][r][3] = 0x7FFFFFFF;
#pragma unroll
          for (int off = 1; off <= 8; off <<= 1) {
            float bs[4]; int bk[4];
#pragma unroll
            for (int q = 0; q < 4; ++q) {
              bs[q] = __shfl_xor(sA[mt][r][q], off, 16);
              bk[q] = __shfl_xor(kA[mt][r][q], off, 16);
            }
            float cs[4]; int ck[4];
#pragma unroll
            for (int q = 0; q < 4; ++q) {
              bool ta = sA[mt][r][q] < bs[3 - q];
              cs[q] = ta ? sA[mt][r][q] : bs[3 - q];
              ck[q] = ta ? kA[mt][r][q] : bk[3 - q];
            }
#define CE(p, q) { bool sw = cs[q] < cs[p]; \
                   float ts = sw ? cs[q] : cs[p]; int tk = sw ? ck[q] : ck[p]; \
                   cs[q] = sw ? cs[p] : cs[q]; ck[q] = sw ? ck[p] : ck[q]; \
                   cs[p] = ts; ck[p] = tk; }
            CE(0, 2) CE(1, 3) CE(0, 1) CE(2, 3)
#undef CE
#pragma unroll
            for (int q = 0; q < 4; ++q) { sA[mt][r][q] = cs[q]; kA[mt][r][q] = ck[q]; }
          }
        }
      int c16 = lane & 15;
#pragma unroll
      for (int slot = 0; slot < 8; ++slot) {
        if (c16 == slot) {
          int mt = slot >> 2, r = slot & 3;
          int row = mt * 16 + quad * 4 + r;
#pragma unroll
          for (int q = 0; q < 4; ++q) {
            candS[row * 16 + wq * 4 + q] = sA[mt][r][q];
            candI[row * 16 + wq * 4 + q] = kA[mt][r][q];
          }
        }
      }
    }
    __syncthreads();

    // ---- ph4: global top-6 per row, easy/hard classification ----
    if (t < 32) {
      float s6[6]; int k6[6];
#pragma unroll
      for (int p = 0; p < 6; ++p) { s6[p] = FLT_MAX; k6[p] = 0x7FFFFFFF; }
      for (int j = 0; j < 16; ++j) {
        float s = candS[t * 16 + j]; int k = candI[t * 16 + j];
#pragma unroll
        for (int p = 0; p < 6; ++p) {
          if (s < s6[p]) {
            float ts = s6[p]; int tk = k6[p];
            s6[p] = s; k6[p] = k; s = ts; k = tk;
          }
        }
      }
      int cnt = 1;
#pragma unroll
      for (int p = 1; p < 6; ++p) if (s6[p] <= s6[0] + MARGIN) cnt++;
      if (cnt == 1) {
        hardCnt[t] = 0;
        idxS[t] = k6[0];
        out[(size_t)IDXOFF + (size_t)c * N_ROWS + rb + t] = (float)k6[0];
        atomicAdd(&counts[c * K_NUM + k6[0]], 1);
      } else {
        hardCnt[t] = cnt;
#pragma unroll
        for (int p = 0; p < 6; ++p) if (p < cnt) hardIdx[t * 6 + p] = k6[p];
      }
    }
    __syncthreads();

    // ---- ph5: hard rows -> exact np rescore (sequential fmaf chain) ----
    {
      int kg = t & 7, rg = t >> 3;
      int cnt = hardCnt[rg];
      if (cnt > 0) {
        float myd = FLT_MAX; int myk = 0x7FFFFFFF;
        if (kg < cnt) {
          int k = hardIdx[rg * 6 + kg];
          const float* wrow = cbl + (size_t)k * DIM;
          float gsum = 0.0f;
#pragma unroll 8
          for (int d = 0; d < DIM; ++d)
            gsum = __builtin_fmaf(wrow[d], resS[SWZ2(rg, d)], gsum);
          float T = sqrS[rg] + sqwl[k];   // fl(sq_r + sq_w)
          myd = T - 2.0f * gsum;          // fl(T - 2g), 2g exact
          myk = k;
        }
#pragma unroll
        for (int off = 1; off <= 4; off <<= 1) {
          float od = __shfl_xor(myd, off, 8);
          int   ok = __shfl_xor(myk, off, 8);
          if (lexless(od, ok, myd, myk)) { myd = od; myk = ok; }
        }
        if (kg == 0) {
          idxS[rg] = myk;
          out[(size_t)IDXOFF + (size_t)c * N_ROWS + rb + rg] = (float)myk;
          atomicAdd(&counts[c * K_NUM + myk], 1);
        }
      }
    }
    __syncthreads();

    // ---- ph6: exact f32 update chain (q_st, quantized, residual, sse) ----
    double lsse = 0.0;
#pragma unroll 4
    for (int i = 0; i < 16; ++i) {
      int it = rh * 16 + i;
      int widx = idxS[it];
      size_t go = (size_t)(rb + it) * DIM + d2 * 2;
      float2 wv = *(const float2*)&cbl[(size_t)widx * DIM + d2 * 2];
      float2 rv = *(const float2*)&resS[SWZV(it, d2)];
      float ex = wv.x - rv.x, ey = wv.y - rv.y;     // e = q - r
      float qsx = rv.x + ex, qsy = rv.y + ey;       // q_st = r + e
      float qnx, qny;
      if (c == 0) { qnx = qsx; qny = qsy; }
      else { float2 qo = *(const float2*)&out[go]; qnx = qo.x + qsx; qny = qo.y + qsy; }
      *(float2*)&out[go] = make_float2(qnx, qny);
      float2 xv = *(const float2*)&x[go];
      float rnx = xv.x - qnx, rny = xv.y - qny;     // res = x - quantized
      *(float2*)&resS[SWZV(it, d2)] = make_float2(rnx, rny);
      lsse += (double)ex * (double)ex + (double)ey * (double)ey;
    }
#pragma unroll
    for (int off = 32; off; off >>= 1) lsse += __shfl_xor(lsse, off, 64);
    if ((t & 63) == 0) atomicAdd(&sse[c], lsse);
    __syncthreads();
  }  // levels
}

// ================= fallback (Round-2 VALU path, needs only 64KB ws) =========
__global__ __launch_bounds__(128) void rvq_main_fb(
    const float* __restrict__ x, const float* __restrict__ cb,
    const float* __restrict__ sqw,
    int* __restrict__ counts, double* __restrict__ sse,
    float* __restrict__ out) {
  __shared__ float Wt[RPB * DIM];
  __shared__ float resS[RPB * DIM];
  int t = threadIdx.x;
  int kg = t & 7;
  int rg = t >> 3;
  int rb = blockIdx.x * RPB;
#pragma unroll 4
  for (int it = 0; it < RPB; ++it) {
    float2 v = *(const float2*)&x[(size_t)(rb + it) * DIM + t * 2];
    *(float2*)&resS[SWZV(it, t)] = v;
  }
  __syncthreads();
  for (int c = 0; c < N_CB; ++c) {
    const float* cbl = cb + (size_t)c * K_NUM * DIM;
    const float* sqwl = sqw + c * K_NUM;
    float sqr[2];
    {
#pragma clang fp contract(off)
#pragma unroll
      for (int j = 0; j < 2; ++j) {
        int row = rg + 16 * j;
        float blk[2];
#pragma unroll
        for (int b = 0; b < 2; ++b) {
          float v0 = resS[SWZ2(row, b * 128 + kg)];
          float acc = v0 * v0;
          for (int i = 1; i < 16; ++i) {
            float v = resS[SWZ2(row, b * 128 + kg + 8 * i)];
            acc = acc + v * v;
          }
          acc = acc + __shfl_xor(acc, 1, 8);
          acc = acc + __shfl_xor(acc, 2, 8);
          acc = acc + __shfl_xor(acc, 4, 8);
          blk[b] = acc;
        }
        sqr[j] = blk[0] + blk[1];
      }
    }
    float m1[2], m2[2]; int i1[2], i2[2];
    m1[0] = m1[1] = m2[0] = m2[1] = FLT_MAX;
    i1[0] = i1[1] = i2[0] = i2[1] = 0x7FFFFFFF;
    for (int tile = 0; tile < K_NUM / 32; ++tile) {
      __syncthreads();
      const float* wsrc = cbl + (size_t)tile * 32 * DIM;
#pragma unroll 4
      for (int it = 0; it < 32; ++it) {
        float2 v = *(const float2*)&wsrc[(size_t)it * DIM + t * 2];
        *(float2*)&Wt[SWZV(it, t)] = v;
      }
      __syncthreads();
      float acc[4][2] = {{0.f, 0.f}, {0.f, 0.f}, {0.f, 0.f}, {0.f, 0.f}};
#pragma unroll 8
      for (int du = 0; du < DIM / 2; ++du) {
        float2 r0 = *(const float2*)&resS[SWZV(rg, du)];
        float2 r1 = *(const float2*)&resS[SWZV(rg + 16, du)];
#pragma unroll
        for (int i = 0; i < 4; ++i) {
          int k = kg + 8 * i;
          float2 w = *(const float2*)&Wt[SWZV(k, du)];
          acc[i][0] += w.x * r0.x; acc[i][0] += w.y * r0.y;
          acc[i][1] += w.x * r1.x; acc[i][1] += w.y * r1.y;
        }
      }
#pragma unroll
      for (int i = 0; i < 4; ++i) {
        int k = tile * 32 + kg + 8 * i;
        float b = sqwl[k];
#pragma unroll
        for (int j = 0; j < 2; ++j) {
          float s = b - 2.0f * acc[i][j];
          if (lexless(s, k, m1[j], i1[j])) {
            m2[j] = m1[j]; i2[j] = i1[j]; m1[j] = s; i1[j] = k;
          } else if (lexless(s, k, m2[j], i2[j])) {
            m2[j] = s; i2[j] = k;
          }
        }
      }
    }
    float as[2][4]; int ak[2][4];
#pragma unroll
    for (int j = 0; j < 2; ++j) {
      as[j][0] = m1[j]; ak[j][0] = i1[j];
      as[j][1] = m2[j]; ak[j][1] = i2[j];
      as[j][2] = FLT_MAX; ak[j][2] = 0x7FFFFFFF;
      as[j][3] = FLT_MAX; ak[j][3] = 0x7FFFFFFF;
#pragma unroll
      for (int off = 1; off <= 4; off <<= 1) {
        float bs[4]; int bk[4];
#pragma unroll
        for (int q = 0; q < 4; ++q) {
          bs[q] = __shfl_xor(as[j][q], off, 8);
          bk[q] = __shfl_xor(ak[j][q], off, 8);
        }
        float cs[4]; int ck[4];
#pragma unroll
        for (int q = 0; q < 4; ++q) {
          bool ta = lexless(as[j][q], ak[j][q], bs[3 - q], bk[3 - q]);
          cs[q] = ta ? as[j][q] : bs[3 - q];
          ck[q] = ta ? ak[j][q] : bk[3 - q];
        }
#define CE(p, q) { bool sw = lexless(cs[q], ck[q], cs[p], ck[p]); \
                   float ts = sw ? cs[q] : cs[p]; int tk = sw ? ck[q] : ck[p]; \
                   cs[q] = sw ? cs[p] : cs[q]; ck[q] = sw ? ck[p] : ck[q]; \
                   cs[p] = ts; ck[p] = tk; }
        CE(0, 2) CE(1, 3) CE(0, 1) CE(2, 3)
#undef CE
#pragma unroll
        for (int q = 0; q < 4; ++q) { as[j][q] = cs[q]; ak[j][q] = ck[q]; }
      }
    }
    int winner[2];
#pragma unroll
    for (int j = 0; j < 2; ++j) {
      if (as[j][1] <= as[j][0] + 1.2e-4f) {
        int row = rg + 16 * j;
        float ss = (kg == 0) ? as[j][0] : (kg == 1) ? as[j][1]
                 : (kg == 2) ? as[j][2] : (kg == 3) ? as[j][3] : FLT_MAX;
        int   sk = (kg == 0) ? ak[j][0] : (kg == 1) ? ak[j][1]
                 : (kg == 2) ? ak[j][2] : (kg == 3) ? ak[j][3] : 0x7FFFFFFF;
        float myd = FLT_MAX; int myk = 0x7FFFFFFF;
        if (kg < 4 && ss <= as[j][0] + 1.2e-4f) {
          const float* wrow = cbl + (size_t)sk * DIM;
          float g = 0.0f;
#pragma unroll 8
          for (int d = 0; d < DIM; ++d)
            g = __builtin_fmaf(wrow[d], resS[SWZ2(row, d)], g);
          float T = sqr[j] + sqwl[sk];
          myd = T - 2.0f * g;
          myk = sk;
        }
#pragma unroll
        for (int off = 1; off <= 4; off <<= 1) {
          float od = __shfl_xor(myd, off, 8);
          int   ok = __shfl_xor(myk, off, 8);
          if (lexless(od, ok, myd, myk)) { myd = od; myk = ok; }
        }
        winner[j] = myk;
      } else {
        winner[j] = ak[j][0];
      }
    }
    __syncthreads();
    int* idxS = (int*)Wt;
    if (kg == 0) {
      idxS[rg] = winner[0];
      idxS[rg + 16] = winner[1];
      out[(size_t)IDXOFF + (size_t)c * N_ROWS + rb + rg] = (float)winner[0];
      out[(size_t)IDXOFF + (size_t)c * N_ROWS + rb + rg + 16] = (float)winner[1];
      atomicAdd(&counts[c * K_NUM + winner[0]], 1);
      atomicAdd(&counts[c * K_NUM + winner[1]], 1);
    }
    __syncthreads();
    double lsse = 0.0;
#pragma unroll 4
    for (int it = 0; it < RPB; ++it) {
      int widx = idxS[it];
      size_t go = (size_t)(rb + it) * DIM + t * 2;
      float2 wv = *(const float2*)&cbl[(size_t)widx * DIM + t * 2];
      float2 rv = *(const float2*)&resS[SWZV(it, t)];
      float ex = wv.x - rv.x, ey = wv.y - rv.y;
      float qsx = rv.x + ex, qsy = rv.y + ey;
      float qnx, qny;
      if (c == 0) { qnx = qsx; qny = qsy; }
      else { float2 qo = *(const float2*)&out[go]; qnx = qo.x + qsx; qny = qo.y + qsy; }
      *(float2*)&out[go] = make_float2(qnx, qny);
      float2 xv = *(const float2*)&x[go];
      float rnx = xv.x - qnx, rny = xv.y - qny;
      *(float2*)&resS[SWZV(it, t)] = make_float2(rnx, rny);
      lsse += (double)ex * (double)ex + (double)ey * (double)ey;
    }
#pragma unroll
    for (int off = 32; off; off >>= 1) lsse += __shfl_xor(lsse, off, 64);
    if ((t & 63) == 0) atomicAdd(&sse[c], lsse);
    __syncthreads();
  }
}

__global__ void finalize_kernel(const int* __restrict__ counts,
                                const double* __restrict__ sse,
                                const double* __restrict__ pdacc,
                                float* __restrict__ out) {
  __shared__ double red[1024];
  int t = threadIdx.x;
  double u = 0.0;
#pragma unroll
  for (int c = 0; c < 4; ++c) u += fabs((double)counts[c * 1024 + t] - 64.0);
  red[t] = u;
  __syncthreads();
  for (int s = 512; s; s >>= 1) {
    if (t < s) red[t] += red[t + s];
    __syncthreads();
  }
  if (t == 0) {
    double q = 0.0;
#pragma unroll
    for (int c = 0; c < 4; ++c) q += sse[c];
    q *= 1.25 / ((double)N_ROWS * (double)DIM);
    out[QOFF + 0] = (float)q;
    out[QOFF + 1] = (float)(red[0] / 1024.0);
    out[QOFF + 2] = (float)(2.0 * pdacc[0] / (double)NPAIRS);
  }
}

extern "C" void kernel_launch(void* const* d_in, const int* in_sizes, int n_in,
                              void* d_out, int out_size, void* d_ws, size_t ws_size,
                              hipStream_t stream) {
  const float* x  = (const float*)d_in[0];
  const float* cb = (const float*)d_in[1];
  float* out = (float*)d_out;

  char* w = (char*)d_ws;
  double* wn64   = (double*)(w);
  float*  sqw    = (float*) (w + 32768);
  int*    counts = (int*)   (w + 49152);
  double* sse    = (double*)(w + 65536);
  double* pdacc  = (double*)(w + 65568);
  _Float16* bws  = (_Float16*)(w + WS_BWS_OFF);

  zero_ws<<<16, 256, 0, stream>>>(counts, sse, pdacc);
  wnorm_kernel<<<1024, 256, 0, stream>>>(cb, wn64);
  np_sqw_kernel<<<16, 256, 0, stream>>>(cb, sqw);
  pdist_kernel<<<4096, 128, 0, stream>>>(cb, wn64, pdacc);
  if (ws_size >= WS_NEEDED) {
    cvt_b_kernel<<<512, 256, 0, stream>>>(cb, bws);
    rvq_main_mfma<<<N_ROWS / RPB, 256, 0, stream>>>(x, cb, bws, sqw, counts, sse, out);
  } else {
    rvq_main_fb<<<N_ROWS / RPB, 128, 0, stream>>>(x, cb, sqw, counts, sse, out);
  }
  finalize_kernel<<<1, 1024, 0, stream>>>(counts, sse, pdacc, out);
}

// Round 4
// 964.706 us; speedup vs baseline: 5.5527x; 1.8485x over previous
//
#include <hip/hip_runtime.h>
#include <math.h>
#include <float.h>

// ResidualVectorQuantizer — Round 4: latency-fix of the fp16-MFMA scorer.
//
// np ref model (verified exact, absmax 0 in R2/R3):
//   G = r @ W.T (sequential-k fmaf), dist = fl(fl(sq_r+sq_w) - fl(2G)),
//   idx = lex-(dist,k) argmin; sq_r/sq_w = numpy pairwise sum (128+128, 8 acc).
// Stage 1 ranks with fp16 MFMA; |np_dist - approx| <= MARGIN; the within-margin
// candidate set is collected exactly and rescored with the exact np formula.

#define N_ROWS 65536
#define DIM    256
#define K_NUM  1024
#define N_CB   4
#define RPB    32
#define QOFF   16777216     // N_ROWS*DIM
#define IDXOFF 16777219     // QOFF + 3 scalars
#define NPAIRS 523776
#define MARGIN 2.4e-4f

#define SWZV(row, dunit) ((row) * DIM + ((((dunit) ^ ((row) & 7))) << 1))
#define SWZ2(row, d)     ((row) * DIM + ((((((d) >> 1) ^ ((row) & 7))) << 1) | ((d) & 1)))
// Af chunk address (in f16 elements), XOR-swizzled for conflict-free wr/rd
#define AFCH(mt, kk, q, m) \
  (((((mt) * 8 + (kk)) * 64) + (q) * 16 + (((m) ^ ((q) << 1) ^ (kk)) & 15)) * 8)

typedef _Float16 f16x8 __attribute__((ext_vector_type(8)));
typedef float    f32x4 __attribute__((ext_vector_type(4)));

// ---------------- ws layout ----------------
// [0, 32768)        double wn64[4096]      (fallback pdist only)
// [32768, 49152)    float  sqw[4096]       (np-exact ||w||^2)
// [49152, 65536)    int    counts[4096]
// [65536, 65568)    double sse[4]
// [65568, 65576)    double pdacc[1]
// [69632, 2166784)  _Float16 bws[1048576]  (fp16 codebooks, fragment-major)
#define WS_BWS_OFF 69632
#define WS_NEEDED  2166784

__device__ __forceinline__ bool lexless(float a, int ka, float b, int kb) {
  return (a < b) || (a == b && ka < kb);
}

__global__ void zero_ws(int* counts, double* sse, double* pdacc) {
  int t = blockIdx.x * blockDim.x + threadIdx.x;
  if (t < 4096) counts[t] = 0;
  if (t < 4) sse[t] = 0.0;
  if (t == 0) pdacc[0] = 0.0;
}

// np-exact sum(W*W, axis=1): pairwise structure for n=256
__global__ void np_sqw_kernel(const float* __restrict__ cb,
                              float* __restrict__ sqw) {
#pragma clang fp contract(off)
  int g = blockIdx.x * blockDim.x + threadIdx.x;  // 0..4095
  const float* row = cb + (size_t)g * DIM;
  float blk[2];
#pragma unroll
  for (int b = 0; b < 2; ++b) {
    const float* a = row + b * 128;
    float r[8];
#pragma unroll
    for (int j = 0; j < 8; ++j) { float v = a[j]; r[j] = v * v; }
    for (int i = 8; i < 128; i += 8) {
#pragma unroll
      for (int j = 0; j < 8; ++j) { float v = a[i + j]; r[j] = r[j] + v * v; }
    }
    blk[b] = ((r[0] + r[1]) + (r[2] + r[3])) + ((r[4] + r[5]) + (r[6] + r[7]));
  }
  sqw[g] = blk[0] + blk[1];
}

// codebooks -> fp16 fragment-major (global layout is linear, lane*8)
__global__ void cvt_b_kernel(const float* __restrict__ cb,
                             _Float16* __restrict__ bws) {
  int tg = blockIdx.x * blockDim.x + threadIdx.x;  // 131072 threads
  int row = tg >> 5;        // 0..4095
  int chunk = tg & 31;
  int c = row >> 10, n = row & 1023;
  int nt = n >> 4, nin = n & 15;
  int kk = chunk >> 2, quad = chunk & 3;
  const float* src = cb + (size_t)row * DIM + chunk * 8;
  f16x8 h;
#pragma unroll
  for (int j = 0; j < 8; ++j) h[j] = (_Float16)src[j];
  size_t dst = ((size_t)((c * 64 + nt) * 8 + kk) * 64 + quad * 16 + nin) * 8;
  *(f16x8*)(bws + dst) = h;
}

// all-pairs mean distance via fp16 MFMA Gram (precision irrelevant: thr 20.48)
__global__ __launch_bounds__(256) void pdist_mfma(
    const _Float16* __restrict__ bws, const float* __restrict__ sqw,
    double* __restrict__ pdacc) {
  int t = threadIdx.x, lane = t & 63, wq = t >> 6;
  int quad = lane >> 4, col = lane & 15;
  int c = blockIdx.x >> 6, iT = blockIdx.x & 63;
  const float* sq = sqw + c * K_NUM;
  const _Float16* base = bws + ((size_t)(c * 64) * 8) * 512 + lane * 8;
  f16x8 Ar[8];
#pragma unroll
  for (int kk = 0; kk < 8; ++kk)
    Ar[kk] = *(const f16x8*)(base + (size_t)(iT * 8 + kk) * 512);
  float bi[4];
#pragma unroll
  for (int r = 0; r < 4; ++r) bi[r] = sq[iT * 16 + quad * 4 + r];
  float sum = 0.f;
#pragma unroll 1
  for (int jt0 = 0; jt0 < 16; ++jt0) {
    int jt = wq * 16 + jt0;
    f16x8 Br[8];
#pragma unroll
    for (int kk = 0; kk < 8; ++kk)
      Br[kk] = *(const f16x8*)(base + (size_t)(jt * 8 + kk) * 512);
    f32x4 acc = {0.f, 0.f, 0.f, 0.f};
#pragma unroll
    for (int kk = 0; kk < 8; ++kk)
      acc = __builtin_amdgcn_mfma_f32_16x16x32_f16(Ar[kk], Br[kk], acc, 0, 0, 0);
    int j = jt * 16 + col;
    float bj = sq[j];
#pragma unroll
    for (int r = 0; r < 4; ++r) {
      int i = iT * 16 + quad * 4 + r;
      float d2 = bi[r] + bj - 2.0f * acc[r];
      if (i != j) sum += sqrtf(fmaxf(d2, 0.f));
    }
  }
  double ds = (double)sum;
#pragma unroll
  for (int off = 32; off; off >>= 1) ds += __shfl_xor(ds, off, 64);
  if (lane == 0) atomicAdd(pdacc, ds);
}

// ================= MFMA main kernel =================
__global__ __launch_bounds__(256, 3) void rvq_main_mfma(
    const float* __restrict__ x, const float* __restrict__ cb,
    const _Float16* __restrict__ bws, const float* __restrict__ sqw,
    int* __restrict__ counts, double* __restrict__ sse,
    float* __restrict__ out) {
  __shared__ float resS[RPB * DIM];                      // 32 KB, swizzled f32
  __shared__ __align__(16) _Float16 Af[16 * 64 * 8];     // 16 KB, persistent frags
  __shared__ float wminS[RPB * 4];
  __shared__ int hardCnt[RPB];
  __shared__ int hardIdx[RPB * 6];
  __shared__ int idxS[RPB];
  __shared__ float sqrS[RPB];

  int t = threadIdx.x;            // 0..255
  int lane = t & 63, wq = t >> 6;
  int quad = lane >> 4, m16 = lane & 15;
  int rb = blockIdx.x * RPB;
  int dchunk = t & 31, rowgrp = t >> 5;   // update/staging mapping (8d chunks)

  // ---- stage: residual = x -> resS (f32) + Af (f16 frags) ----
#pragma unroll
  for (int i = 0; i < 4; ++i) {
    int row = rowgrp * 4 + i;
    size_t go = (size_t)(rb + row) * DIM + dchunk * 8;
    float xv[8];
    *(float4*)&xv[0] = *(const float4*)&x[go];
    *(float4*)&xv[4] = *(const float4*)&x[go + 4];
    f16x8 h;
#pragma unroll
    for (int j = 0; j < 8; ++j) h[j] = (_Float16)xv[j];
    *(f16x8*)(Af + AFCH(row >> 4, dchunk >> 2, dchunk & 3, row & 15)) = h;
    int u0 = dchunk * 4;
    *(float2*)&resS[SWZV(row, u0 + 0)] = make_float2(xv[0], xv[1]);
    *(float2*)&resS[SWZV(row, u0 + 1)] = make_float2(xv[2], xv[3]);
    *(float2*)&resS[SWZV(row, u0 + 2)] = make_float2(xv[4], xv[5]);
    *(float2*)&resS[SWZV(row, u0 + 3)] = make_float2(xv[6], xv[7]);
  }
  __syncthreads();

  for (int c = 0; c < N_CB; ++c) {
    const float* cbl = cb + (size_t)c * K_NUM * DIM;
    const float* sqwl = sqw + c * K_NUM;

    // ---- ph0: np-exact sq_r per row (8-lane pairwise replica) ----
    {
#pragma clang fp contract(off)
      int kg = t & 7, rg = t >> 3;
      float blk[2];
#pragma unroll
      for (int b = 0; b < 2; ++b) {
        float v0 = resS[SWZ2(rg, b * 128 + kg)];
        float acc = v0 * v0;
        for (int i = 1; i < 16; ++i) {
          float v = resS[SWZ2(rg, b * 128 + kg + 8 * i)];
          acc = acc + v * v;
        }
        acc = acc + __shfl_xor(acc, 1, 8);
        acc = acc + __shfl_xor(acc, 2, 8);
        acc = acc + __shfl_xor(acc, 4, 8);
        blk[b] = acc;
      }
      if (kg == 0) sqrS[rg] = blk[0] + blk[1];
    }

    // ---- ph2: MFMA scoring (A hoisted to regs, B streamed from L2) ----
    f16x8 Ar[2][8];
#pragma unroll
    for (int kk = 0; kk < 8; ++kk) {
      Ar[0][kk] = *(const f16x8*)(Af + AFCH(0, kk, quad, m16));
      Ar[1][kk] = *(const f16x8*)(Af + AFCH(1, kk, quad, m16));
    }
    float s1[2][4], s2[2][4]; int k1[2][4], k2[2][4];
#pragma unroll
    for (int mt = 0; mt < 2; ++mt)
#pragma unroll
      for (int r = 0; r < 4; ++r) {
        s1[mt][r] = FLT_MAX; s2[mt][r] = FLT_MAX;
        k1[mt][r] = 0x7FFFFFFF; k2[mt][r] = 0x7FFFFFFF;
      }
    const _Float16* Bc = bws + (size_t)((c * 64 + wq * 16) * 8) * 512 + lane * 8;
#pragma unroll 1
    for (int nt = 0; nt < 16; ++nt) {
      const _Float16* Bp = Bc + (size_t)nt * 8 * 512;
      f16x8 Br[8];
#pragma unroll
      for (int kk = 0; kk < 8; ++kk)
        Br[kk] = *(const f16x8*)(Bp + (size_t)kk * 512);
      f32x4 acc0 = {0.f, 0.f, 0.f, 0.f}, acc1 = {0.f, 0.f, 0.f, 0.f};
#pragma unroll
      for (int kk = 0; kk < 8; ++kk) {
        acc0 = __builtin_amdgcn_mfma_f32_16x16x32_f16(Ar[0][kk], Br[kk], acc0, 0, 0, 0);
        acc1 = __builtin_amdgcn_mfma_f32_16x16x32_f16(Ar[1][kk], Br[kk], acc1, 0, 0, 0);
      }
      int n = (wq * 16 + nt) * 16 + m16;
      float w2 = sqwl[n];
#pragma unroll
      for (int r = 0; r < 4; ++r) {
        float sa = w2 - 2.0f * acc0[r];
        if (sa < s1[0][r]) { s2[0][r] = s1[0][r]; k2[0][r] = k1[0][r]; s1[0][r] = sa; k1[0][r] = n; }
        else if (sa < s2[0][r]) { s2[0][r] = sa; k2[0][r] = n; }
        float sb = w2 - 2.0f * acc1[r];
        if (sb < s1[1][r]) { s2[1][r] = s1[1][r]; k2[1][r] = k1[1][r]; s1[1][r] = sb; k1[1][r] = n; }
        else if (sb < s2[1][r]) { s2[1][r] = sb; k2[1][r] = n; }
      }
    }

    // ---- step1: per-wave row-min -> wminS; zero hardCnt ----
    if (t < RPB) hardCnt[t] = 0;
#pragma unroll
    for (int mt = 0; mt < 2; ++mt)
#pragma unroll
      for (int r = 0; r < 4; ++r) {
        float mn = s1[mt][r];
#pragma unroll
        for (int off = 1; off <= 8; off <<= 1)
          mn = fminf(mn, __shfl_xor(mn, off, 16));
        if (m16 == 0) wminS[(mt * 16 + quad * 4 + r) * 4 + wq] = mn;
      }
    __syncthreads();

    // ---- step2: global thr; collect within-margin candidates via LDS atomics
#pragma unroll
    for (int mt = 0; mt < 2; ++mt)
#pragma unroll
      for (int r = 0; r < 4; ++r) {
        int row = mt * 16 + quad * 4 + r;
        float thr = fminf(fminf(wminS[row * 4 + 0], wminS[row * 4 + 1]),
                          fminf(wminS[row * 4 + 2], wminS[row * 4 + 3])) + MARGIN;
        bool c1 = s1[mt][r] <= thr;
        if (c1) {
          bool c2 = s2[mt][r] <= thr;
          int pos = atomicAdd(&hardCnt[row], 1 + (c2 ? 1 : 0));
          if (pos < 6) hardIdx[row * 6 + pos] = k1[mt][r];
          if (c2 && pos + 1 < 6) hardIdx[row * 6 + pos + 1] = k2[mt][r];
        }
      }
    __syncthreads();

    // ---- ph5: winner per row (cnt==1 fast; else exact np rescore) ----
    {
      int kg = t & 7, rg = t >> 3;
      int cnt = hardCnt[rg]; if (cnt > 6) cnt = 6;
      int winner;
      if (cnt == 1) {
        winner = hardIdx[rg * 6];
      } else {
        float myd = FLT_MAX; int myk = 0x7FFFFFFF;
        if (kg < cnt) {
          int k = hardIdx[rg * 6 + kg];
          const float* wrow = cbl + (size_t)k * DIM;
          float gsum = 0.0f;
#pragma unroll 8
          for (int d = 0; d < DIM; ++d)
            gsum = __builtin_fmaf(wrow[d], resS[SWZ2(rg, d)], gsum);
          float T = sqrS[rg] + sqwl[k];   // fl(sq_r + sq_w)
          myd = T - 2.0f * gsum;          // fl(T - 2g), 2g exact
          myk = k;
        }
#pragma unroll
        for (int off = 1; off <= 4; off <<= 1) {
          float od = __shfl_xor(myd, off, 8);
          int   ok = __shfl_xor(myk, off, 8);
          if (lexless(od, ok, myd, myk)) { myd = od; myk = ok; }
        }
        winner = myk;
      }
      if (kg == 0) {
        idxS[rg] = winner;
        out[(size_t)IDXOFF + (size_t)c * N_ROWS + rb + rg] = (float)winner;
        atomicAdd(&counts[c * K_NUM + winner], 1);
      }
    }
    __syncthreads();

    // ---- ph6: exact f32 update chain; writes out, resS, next-level Af ----
    double lsse = 0.0;
#pragma unroll
    for (int i = 0; i < 4; ++i) {
      int row = rowgrp * 4 + i;
      int widx = idxS[row];
      size_t go = (size_t)(rb + row) * DIM + dchunk * 8;
      float xv[8], wv[8], qv[8];
      *(float4*)&xv[0] = *(const float4*)&x[go];
      *(float4*)&xv[4] = *(const float4*)&x[go + 4];
      const float* wrow = cbl + (size_t)widx * DIM + dchunk * 8;
      *(float4*)&wv[0] = *(const float4*)&wrow[0];
      *(float4*)&wv[4] = *(const float4*)&wrow[4];
      if (c != 0) {
        *(float4*)&qv[0] = *(const float4*)&out[go];
        *(float4*)&qv[4] = *(const float4*)&out[go + 4];
      }
      f16x8 h;
      float rnv[8];
#pragma unroll
      for (int j = 0; j < 8; ++j) {
        float rv = (c == 0) ? xv[j] : (xv[j] - qv[j]);  // == stored residual, bit-exact
        float e = wv[j] - rv;                            // e = q - r
        float qs = rv + e;                               // q_st
        float qn = (c == 0) ? qs : (qv[j] + qs);         // quantized accum
        qv[j] = qn;
        float rn = xv[j] - qn;                           // next residual
        rnv[j] = rn;
        h[j] = (_Float16)rn;
        lsse += (double)e * (double)e;
      }
      *(float4*)&out[go] = *(const float4*)&qv[0];
      *(float4*)&out[go + 4] = *(const float4*)&qv[4];
      *(f16x8*)(Af + AFCH(row >> 4, dchunk >> 2, dchunk & 3, row & 15)) = h;
      int u0 = dchunk * 4;
      *(float2*)&resS[SWZV(row, u0 + 0)] = make_float2(rnv[0], rnv[1]);
      *(float2*)&resS[SWZV(row, u0 + 1)] = make_float2(rnv[2], rnv[3]);
      *(float2*)&resS[SWZV(row, u0 + 2)] = make_float2(rnv[4], rnv[5]);
      *(float2*)&resS[SWZV(row, u0 + 3)] = make_float2(rnv[6], rnv[7]);
    }
#pragma unroll
    for (int off = 32; off; off >>= 1) lsse += __shfl_xor(lsse, off, 64);
    if ((t & 63) == 0) atomicAdd(&sse[c], lsse);
    __syncthreads();
  }  // levels
}

// ================= fallback path (small ws): R2 VALU kernels ================
__global__ void wnorm_kernel(const float* __restrict__ cb,
                             double* __restrict__ wn64) {
  int gw = blockIdx.x * 4 + (threadIdx.x >> 6);
  int lane = threadIdx.x & 63;
  const float* row = cb + (size_t)gw * DIM;
  float4 v = *(const float4*)(row + lane * 4);
  double s = (double)v.x * v.x + (double)v.y * v.y +
             (double)v.z * v.z + (double)v.w * v.w;
#pragma unroll
  for (int off = 32; off; off >>= 1) s += __shfl_xor(s, off, 64);
  if (lane == 0) wn64[gw] = s;
}

__global__ void pdist_kernel(const float* __restrict__ cb,
                             const double* __restrict__ wn64,
                             double* __restrict__ pdacc) {
  __shared__ float wi[DIM];
  int c = blockIdx.x >> 10;
  int i = blockIdx.x & 1023;
  int t = threadIdx.x;  // 128
  const float* rowi = cb + ((size_t)c * K_NUM + i) * DIM;
  *(float2*)&wi[t * 2] = *(const float2*)&rowi[t * 2];
  __syncthreads();
  double bi = wn64[c * K_NUM + i];
  double lsum = 0.0;
  for (int j = i + 1 + t; j < K_NUM; j += 128) {
    const float* rowj = cb + ((size_t)c * K_NUM + j) * DIM;
    double dot = 0.0;
#pragma unroll 8
    for (int d = 0; d < DIM; ++d) dot += (double)rowj[d] * (double)wi[d];
    double d2 = bi + wn64[c * K_NUM + j] - 2.0 * dot;
    lsum += sqrt(fmax(d2, 0.0));
  }
#pragma unroll
  for (int off = 32; off; off >>= 1) lsum += __shfl_xor(lsum, off, 64);
  if ((t & 63) == 0) atomicAdd(pdacc, lsum);
}

__global__ __launch_bounds__(128) void rvq_main_fb(
    const float* __restrict__ x, const float* __restrict__ cb,
    const float* __restrict__ sqw,
    int* __restrict__ counts, double* __restrict__ sse,
    float* __restrict__ out) {
  __shared__ float Wt[RPB * DIM];
  __shared__ float resS[RPB * DIM];
  int t = threadIdx.x;
  int kg = t & 7;
  int rg = t >> 3;
  int rb = blockIdx.x * RPB;
#pragma unroll 4
  for (int it = 0; it < RPB; ++it) {
    float2 v = *(const float2*)&x[(size_t)(rb + it) * DIM + t * 2];
    *(float2*)&resS[SWZV(it, t)] = v;
  }
  __syncthreads();
  for (int c = 0; c < N_CB; ++c) {
    const float* cbl = cb + (size_t)c * K_NUM * DIM;
    const float* sqwl = sqw + c * K_NUM;
    float sqr[2];
    {
#pragma clang fp contract(off)
#pragma unroll
      for (int j = 0; j < 2; ++j) {
        int row = rg + 16 * j;
        float blk[2];
#pragma unroll
        for (int b = 0; b < 2; ++b) {
          float v0 = resS[SWZ2(row, b * 128 + kg)];
          float acc = v0 * v0;
          for (int i = 1; i < 16; ++i) {
            float v = resS[SWZ2(row, b * 128 + kg + 8 * i)];
            acc = acc + v * v;
          }
          acc = acc + __shfl_xor(acc, 1, 8);
          acc = acc + __shfl_xor(acc, 2, 8);
          acc = acc + __shfl_xor(acc, 4, 8);
          blk[b] = acc;
        }
        sqr[j] = blk[0] + blk[1];
      }
    }
    float m1[2], m2[2]; int i1[2], i2[2];
    m1[0] = m1[1] = m2[0] = m2[1] = FLT_MAX;
    i1[0] = i1[1] = i2[0] = i2[1] = 0x7FFFFFFF;
    for (int tile = 0; tile < K_NUM / 32; ++tile) {
      __syncthreads();
      const float* wsrc = cbl + (size_t)tile * 32 * DIM;
#pragma unroll 4
      for (int it = 0; it < 32; ++it) {
        float2 v = *(const float2*)&wsrc[(size_t)it * DIM + t * 2];
        *(float2*)&Wt[SWZV(it, t)] = v;
      }
      __syncthreads();
      float acc[4][2] = {{0.f, 0.f}, {0.f, 0.f}, {0.f, 0.f}, {0.f, 0.f}};
#pragma unroll 8
      for (int du = 0; du < DIM / 2; ++du) {
        float2 r0 = *(const float2*)&resS[SWZV(rg, du)];
        float2 r1 = *(const float2*)&resS[SWZV(rg + 16, du)];
#pragma unroll
        for (int i = 0; i < 4; ++i) {
          int k = kg + 8 * i;
          float2 w = *(const float2*)&Wt[SWZV(k, du)];
          acc[i][0] += w.x * r0.x; acc[i][0] += w.y * r0.y;
          acc[i][1] += w.x * r1.x; acc[i][1] += w.y * r1.y;
        }
      }
#pragma unroll
      for (int i = 0; i < 4; ++i) {
        int k = tile * 32 + kg + 8 * i;
        float b = sqwl[k];
#pragma unroll
        for (int j = 0; j < 2; ++j) {
          float s = b - 2.0f * acc[i][j];
          if (lexless(s, k, m1[j], i1[j])) {
            m2[j] = m1[j]; i2[j] = i1[j]; m1[j] = s; i1[j] = k;
          } else if (lexless(s, k, m2[j], i2[j])) {
            m2[j] = s; i2[j] = k;
          }
        }
      }
    }
    float as[2][4]; int ak[2][4];
#pragma unroll
    for (int j = 0; j < 2; ++j) {
      as[j][0] = m1[j]; ak[j][0] = i1[j];
      as[j][1] = m2[j]; ak[j][1] = i2[j];
      as[j][2] = FLT_MAX; ak[j][2] = 0x7FFFFFFF;
      as[j][3] = FLT_MAX; ak[j][3] = 0x7FFFFFFF;
#pragma unroll
      for (int off = 1; off <= 4; off <<= 1) {
        float bs[4]; int bk[4];
#pragma unroll
        for (int q = 0; q < 4; ++q) {
          bs[q] = __shfl_xor(as[j][q], off, 8);
          bk[q] = __shfl_xor(ak[j][q], off, 8);
        }
        float cs[4]; int ck[4];
#pragma unroll
        for (int q = 0; q < 4; ++q) {
          bool ta = lexless(as[j][q], ak[j][q], bs[3 - q], bk[3 - q]);
          cs[q] = ta ? as[j][q] : bs[3 - q];
          ck[q] = ta ? ak[j][q] : bk[3 - q];
        }
#define CE(p, q) { bool sw = lexless(cs[q], ck[q], cs[p], ck[p]); \
                   float ts = sw ? cs[q] : cs[p]; int tk = sw ? ck[q] : ck[p]; \
                   cs[q] = sw ? cs[p] : cs[q]; ck[q] = sw ? ck[p] : ck[q]; \
                   cs[p] = ts; ck[p] = tk; }
        CE(0, 2) CE(1, 3) CE(0, 1) CE(2, 3)
#undef CE
#pragma unroll
        for (int q = 0; q < 4; ++q) { as[j][q] = cs[q]; ak[j][q] = ck[q]; }
      }
    }
    int winner[2];
#pragma unroll
    for (int j = 0; j < 2; ++j) {
      if (as[j][1] <= as[j][0] + 1.2e-4f) {
        int row = rg + 16 * j;
        float ss = (kg == 0) ? as[j][0] : (kg == 1) ? as[j][1]
                 : (kg == 2) ? as[j][2] : (kg == 3) ? as[j][3] : FLT_MAX;
        int   sk = (kg == 0) ? ak[j][0] : (kg == 1) ? ak[j][1]
                 : (kg == 2) ? ak[j][2] : (kg == 3) ? ak[j][3] : 0x7FFFFFFF;
        float myd = FLT_MAX; int myk = 0x7FFFFFFF;
        if (kg < 4 && ss <= as[j][0] + 1.2e-4f) {
          const float* wrow = cbl + (size_t)sk * DIM;
          float g = 0.0f;
#pragma unroll 8
          for (int d = 0; d < DIM; ++d)
            g = __builtin_fmaf(wrow[d], resS[SWZ2(row, d)], g);
          float T = sqr[j] + sqwl[sk];
          myd = T - 2.0f * g;
          myk = sk;
        }
#pragma unroll
        for (int off = 1; off <= 4; off <<= 1) {
          float od = __shfl_xor(myd, off, 8);
          int   ok = __shfl_xor(myk, off, 8);
          if (lexless(od, ok, myd, myk)) { myd = od; myk = ok; }
        }
        winner[j] = myk;
      } else {
        winner[j] = ak[j][0];
      }
    }
    __syncthreads();
    int* idxSf = (int*)Wt;
    if (kg == 0) {
      idxSf[rg] = winner[0];
      idxSf[rg + 16] = winner[1];
      out[(size_t)IDXOFF + (size_t)c * N_ROWS + rb + rg] = (float)winner[0];
      out[(size_t)IDXOFF + (size_t)c * N_ROWS + rb + rg + 16] = (float)winner[1];
      atomicAdd(&counts[c * K_NUM + winner[0]], 1);
      atomicAdd(&counts[c * K_NUM + winner[1]], 1);
    }
    __syncthreads();
    double lsse = 0.0;
#pragma unroll 4
    for (int it = 0; it < RPB; ++it) {
      int widx = idxSf[it];
      size_t go = (size_t)(rb + it) * DIM + t * 2;
      float2 wv = *(const float2*)&cbl[(size_t)widx * DIM + t * 2];
      float2 rv = *(const float2*)&resS[SWZV(it, t)];
      float ex = wv.x - rv.x, ey = wv.y - rv.y;
      float qsx = rv.x + ex, qsy = rv.y + ey;
      float qnx, qny;
      if (c == 0) { qnx = qsx; qny = qsy; }
      else { float2 qo = *(const float2*)&out[go]; qnx = qo.x + qsx; qny = qo.y + qsy; }
      *(float2*)&out[go] = make_float2(qnx, qny);
      float2 xv = *(const float2*)&x[go];
      float rnx = xv.x - qnx, rny = xv.y - qny;
      *(float2*)&resS[SWZV(it, t)] = make_float2(rnx, rny);
      lsse += (double)ex * (double)ex + (double)ey * (double)ey;
    }
#pragma unroll
    for (int off = 32; off; off >>= 1) lsse += __shfl_xor(lsse, off, 64);
    if ((t & 63) == 0) atomicAdd(&sse[c], lsse);
    __syncthreads();
  }
}

__global__ void finalize_kernel(const int* __restrict__ counts,
                                const double* __restrict__ sse,
                                const double* __restrict__ pdacc,
                                float* __restrict__ out, double pdscale) {
  __shared__ double red[1024];
  int t = threadIdx.x;
  double u = 0.0;
#pragma unroll
  for (int c = 0; c < 4; ++c) u += fabs((double)counts[c * 1024 + t] - 64.0);
  red[t] = u;
  __syncthreads();
  for (int s = 512; s; s >>= 1) {
    if (t < s) red[t] += red[t + s];
    __syncthreads();
  }
  if (t == 0) {
    double q = 0.0;
#pragma unroll
    for (int c = 0; c < 4; ++c) q += sse[c];
    q *= 1.25 / ((double)N_ROWS * (double)DIM);
    out[QOFF + 0] = (float)q;
    out[QOFF + 1] = (float)(red[0] / 1024.0);
    out[QOFF + 2] = (float)(pdscale * pdacc[0] / (double)NPAIRS);
  }
}

extern "C" void kernel_launch(void* const* d_in, const int* in_sizes, int n_in,
                              void* d_out, int out_size, void* d_ws, size_t ws_size,
                              hipStream_t stream) {
  const float* x  = (const float*)d_in[0];
  const float* cb = (const float*)d_in[1];
  float* out = (float*)d_out;

  char* w = (char*)d_ws;
  double* wn64   = (double*)(w);
  float*  sqw    = (float*) (w + 32768);
  int*    counts = (int*)   (w + 49152);
  double* sse    = (double*)(w + 65536);
  double* pdacc  = (double*)(w + 65568);
  _Float16* bws  = (_Float16*)(w + WS_BWS_OFF);

  zero_ws<<<16, 256, 0, stream>>>(counts, sse, pdacc);
  np_sqw_kernel<<<16, 256, 0, stream>>>(cb, sqw);
  if (ws_size >= WS_NEEDED) {
    cvt_b_kernel<<<512, 256, 0, stream>>>(cb, bws);
    pdist_mfma<<<256, 256, 0, stream>>>(bws, sqw, pdacc);
    rvq_main_mfma<<<N_ROWS / RPB, 256, 0, stream>>>(x, cb, bws, sqw, counts, sse, out);
    finalize_kernel<<<1, 1024, 0, stream>>>(counts, sse, pdacc, out, 1.0);
  } else {
    wnorm_kernel<<<1024, 256, 0, stream>>>(cb, wn64);
    pdist_kernel<<<4096, 128, 0, stream>>>(cb, wn64, pdacc);
    rvq_main_fb<<<N_ROWS / RPB, 128, 0, stream>>>(x, cb, sqw, counts, sse, out);
    finalize_kernel<<<1, 1024, 0, stream>>>(counts, sse, pdacc, out, 2.0);
  }
}